// Round 1
// baseline (537.373 us; speedup 1.0000x reference)
//
#include <hip/hip_runtime.h>
#include <hip/hip_bf16.h>

// ---------------------------------------------------------------------------
// Problem: N=2, S=2048, C=1024, A=1024, H=16, d=64, MAXLEN=2048
// Outputs: y [2,2048,1024] fp32  then  attn [2,16,2048,2048] fp32 (concat flat)
// ---------------------------------------------------------------------------

typedef __attribute__((ext_vector_type(8))) short s16x8;   // 8 x bf16 bits (4 VGPR)
typedef __attribute__((ext_vector_type(4))) float f32x4;   // MFMA acc

#define NEGV (-1e30f)

static __device__ __forceinline__ short f2bf(float f) {
  // round-to-nearest-even fp32 -> bf16 (no NaN in this problem)
  unsigned u = __float_as_uint(f);
  unsigned r = (u + 0x7fffu + ((u >> 16) & 1u)) >> 16;
  return (short)r;
}

// ---------------- elementwise cast fp32 -> bf16 ----------------------------
__global__ void cast_f32_bf16(const float* __restrict__ in, short* __restrict__ out, int n) {
  int i = (blockIdx.x * 256 + threadIdx.x) * 8;
  if (i >= n) return;
  float4 a = *(const float4*)&in[i];
  float4 b = *(const float4*)&in[i + 4];
  s16x8 v;
  v[0] = f2bf(a.x); v[1] = f2bf(a.y); v[2] = f2bf(a.z); v[3] = f2bf(a.w);
  v[4] = f2bf(b.x); v[5] = f2bf(b.y); v[6] = f2bf(b.z); v[7] = f2bf(b.w);
  *(s16x8*)&out[i] = v;
}

// ---------------- transpose + cast: [R][Cc] fp32 -> [Cc][R] bf16 -----------
__global__ void transpose_cast(const float* __restrict__ in, short* __restrict__ out,
                               int R, int Cc) {
  __shared__ float tile[32][33];
  int c0 = blockIdx.x * 32, r0 = blockIdx.y * 32;
  int tx = threadIdx.x, ty = threadIdx.y;          // block (32,8)
  for (int i = 0; i < 32; i += 8)
    tile[ty + i][tx] = in[(size_t)(r0 + ty + i) * Cc + c0 + tx];
  __syncthreads();
  for (int i = 0; i < 32; i += 8)
    out[(size_t)(c0 + ty + i) * R + r0 + tx] = f2bf(tile[tx][ty + i]);
}

// ---------------- rel_table [2048][16] fp32 -> [16][2048] fp32 -------------
__global__ void transpose_table_k(const float* __restrict__ in, float* __restrict__ out) {
  int i = blockIdx.x * 256 + threadIdx.x;          // 0..32767
  if (i >= 2048 * 16) return;
  int l = i >> 4, h = i & 15;
  out[h * 2048 + l] = in[i];
}

// ---------------- bf16 MFMA GEMM: C = A[M][K] * BT[Nn][K]^T ----------------
// 128x128 tile, BK=64, 4 waves (2x2), each wave 64x64 via 4x4 16x16x32 frags.
template<bool OUT_F32>
__global__ __launch_bounds__(256) void gemm_bt(
    const short* __restrict__ A, const short* __restrict__ BT,
    void* __restrict__ Cout, int M, int Nn, int K)
{
  __shared__ short As[128][72];   // +8 pad: conflict-light, keeps 16B alignment
  __shared__ short Bs[128][72];
  int bn = blockIdx.x, bm = blockIdx.y;
  int tid = threadIdx.x, wave = tid >> 6, lane = tid & 63;
  int wr = wave >> 1, wc = wave & 1;
  int lc = lane & 15, lg = lane >> 4;
  f32x4 acc[4][4];
  for (int i = 0; i < 4; ++i)
    for (int j = 0; j < 4; ++j) acc[i][j] = (f32x4){0.f, 0.f, 0.f, 0.f};
  const short* Abase = A  + (size_t)(bm * 128) * K;
  const short* Bbase = BT + (size_t)(bn * 128) * K;
  for (int k0 = 0; k0 < K; k0 += 64) {
    __syncthreads();
    for (int it = 0; it < 4; ++it) {               // 128x64 each, 8 chunks/row
      int lid = tid + it * 256;
      int r = lid >> 3, ck = (lid & 7) * 8;
      *(s16x8*)&As[r][ck] = *(const s16x8*)&Abase[(size_t)r * K + k0 + ck];
      *(s16x8*)&Bs[r][ck] = *(const s16x8*)&Bbase[(size_t)r * K + k0 + ck];
    }
    __syncthreads();
    for (int ks = 0; ks < 2; ++ks) {
      s16x8 af[4], bfr[4];
      for (int mi = 0; mi < 4; ++mi)
        af[mi] = *(const s16x8*)&As[wr * 64 + mi * 16 + lc][ks * 32 + lg * 8];
      for (int ni = 0; ni < 4; ++ni)
        bfr[ni] = *(const s16x8*)&Bs[wc * 64 + ni * 16 + lc][ks * 32 + lg * 8];
      for (int mi = 0; mi < 4; ++mi)
        for (int ni = 0; ni < 4; ++ni)
          acc[mi][ni] = __builtin_amdgcn_mfma_f32_16x16x32_bf16(af[mi], bfr[ni], acc[mi][ni], 0, 0, 0);
    }
  }
  int row0 = bm * 128 + wr * 64, col0 = bn * 128 + wc * 64;
  for (int mi = 0; mi < 4; ++mi)
    for (int ni = 0; ni < 4; ++ni)
      for (int r = 0; r < 4; ++r) {
        int row = row0 + mi * 16 + lg * 4 + r;     // C/D: col=lane&15, row=(lane>>4)*4+r
        int col = col0 + ni * 16 + lc;
        if constexpr (OUT_F32)
          ((float*)Cout)[(size_t)row * Nn + col] = acc[mi][ni][r];
        else
          ((short*)Cout)[(size_t)row * Nn + col] = f2bf(acc[mi][ni][r]);
      }
}

// ---------------- fused attention ------------------------------------------
// grid (qt=S/64, h=16, n=2), 256 threads (4 waves). Two-pass softmax:
//   pass1: running row max+sum over causal K-tiles
//   pass2: recompute logits, write normalized attn (fp32), accumulate PV.
// Upper-triangle tiles written as zeros (attn bytes written exactly once).
__global__ __launch_bounds__(256) void attn_fused(
    const short* __restrict__ qkv,     // [4096][3072] bf16: q|k|v, head-major d=64
    const int*   __restrict__ mask,    // [2][2048] int (0/1)
    const float* __restrict__ tableT,  // [16][2048]
    float* __restrict__ attn_out,      // [2][16][2048][2048]
    short* __restrict__ y_ws)          // [4096][1024] bf16
{
  int qt = blockIdx.x, h = blockIdx.y, n = blockIdx.z;
  int tid = threadIdx.x, wave = tid >> 6, lane = tid & 63;
  int lc = lane & 15, lg = lane >> 4;

  __shared__ short Qs[64][72];
  __shared__ short Ks[64][72];
  __shared__ short VTs[64][72];   // V transposed: [dd][k]
  __shared__ short Ps[64][72];
  __shared__ float btab[2048];
  __shared__ unsigned char mk[2048];

  for (int i = tid; i < 2048; i += 256) {
    btab[i] = tableT[h * 2048 + i];
    mk[i] = (unsigned char)(mask[n * 2048 + i] != 0);
  }

  const size_t rowbase = (size_t)(n * 2048 + qt * 64);
  const short* qbase = qkv + rowbase * 3072 + h * 64;
  for (int it = 0; it < 2; ++it) {
    int lid = tid + it * 256;
    int r = lid >> 3, ck = (lid & 7) * 8;
    *(s16x8*)&Qs[r][ck] = *(const s16x8*)&qbase[(size_t)r * 3072 + ck];
  }
  __syncthreads();

  s16x8 aq[2];                                  // Q frags: rows wave*16..+15
  for (int ks = 0; ks < 2; ++ks)
    aq[ks] = *(const s16x8*)&Qs[wave * 16 + lc][ks * 32 + lg * 8];

  int qrow[4];
  for (int r = 0; r < 4; ++r) qrow[r] = qt * 64 + wave * 16 + lg * 4 + r;

  float m[4], l[4];
  for (int r = 0; r < 4; ++r) { m[r] = NEGV; l[r] = 0.f; }

  // ---------------- pass 1: row max + sum ----------------
  for (int kt = 0; kt <= qt; ++kt) {
    __syncthreads();
    const short* kbase = qkv + (size_t)(n * 2048 + kt * 64) * 3072 + 1024 + h * 64;
    for (int it = 0; it < 2; ++it) {
      int lid = tid + it * 256;
      int r = lid >> 3, ck = (lid & 7) * 8;
      *(s16x8*)&Ks[r][ck] = *(const s16x8*)&kbase[(size_t)r * 3072 + ck];
    }
    __syncthreads();

    f32x4 c[4];
    for (int ni = 0; ni < 4; ++ni) {
      c[ni] = (f32x4){0.f, 0.f, 0.f, 0.f};
      for (int ks = 0; ks < 2; ++ks) {
        s16x8 b = *(const s16x8*)&Ks[ni * 16 + lc][ks * 32 + lg * 8];
        c[ni] = __builtin_amdgcn_mfma_f32_16x16x32_bf16(aq[ks], b, c[ni], 0, 0, 0);
      }
    }
    for (int r = 0; r < 4; ++r) {
      float vals[4], tmax = NEGV;
      for (int ni = 0; ni < 4; ++ni) {
        int col = kt * 64 + ni * 16 + lc;
        bool ok = (col <= qrow[r]) && mk[col];
        float v = ok ? c[ni][r] * 0.125f + btab[qrow[r] - col] : NEGV;
        vals[ni] = v;
        tmax = fmaxf(tmax, v);
      }
      for (int off = 1; off < 16; off <<= 1)
        tmax = fmaxf(tmax, __shfl_xor(tmax, off));
      float mn = fmaxf(m[r], tmax);
      float s = 0.f;
      for (int ni = 0; ni < 4; ++ni) s += __expf(vals[ni] - mn);
      for (int off = 1; off < 16; off <<= 1)
        s += __shfl_xor(s, off);
      l[r] = l[r] * __expf(m[r] - mn) + s;
      m[r] = mn;
    }
  }

  float rinv[4];
  bool qvalid[4];
  for (int r = 0; r < 4; ++r) {
    rinv[r] = 1.0f / l[r];                        // l>=1 always (see analysis)
    qvalid[r] = (mk[qrow[r]] != 0);
  }

  f32x4 yacc[4];
  for (int ni = 0; ni < 4; ++ni) yacc[ni] = (f32x4){0.f, 0.f, 0.f, 0.f};

  float* aout = attn_out + (size_t)(n * 16 + h) * 2048 * 2048;

  // ---------------- pass 2: normalized attn + PV ----------------
  for (int kt = 0; kt < 32; ++kt) {
    if (kt <= qt) {
      __syncthreads();
      const short* kbase = qkv + (size_t)(n * 2048 + kt * 64) * 3072 + 1024 + h * 64;
      const short* vbase = qkv + (size_t)(n * 2048 + kt * 64) * 3072 + 2048 + h * 64;
      for (int it = 0; it < 2; ++it) {
        int lid = tid + it * 256;
        int r = lid >> 3, ck = (lid & 7) * 8;
        *(s16x8*)&Ks[r][ck] = *(const s16x8*)&kbase[(size_t)r * 3072 + ck];
        s16x8 v = *(const s16x8*)&vbase[(size_t)r * 3072 + ck];
        for (int j = 0; j < 8; ++j) VTs[ck + j][r] = v[j];   // transpose into LDS
      }
      __syncthreads();

      f32x4 c[4];
      for (int ni = 0; ni < 4; ++ni) {
        c[ni] = (f32x4){0.f, 0.f, 0.f, 0.f};
        for (int ks = 0; ks < 2; ++ks) {
          s16x8 b = *(const s16x8*)&Ks[ni * 16 + lc][ks * 32 + lg * 8];
          c[ni] = __builtin_amdgcn_mfma_f32_16x16x32_bf16(aq[ks], b, c[ni], 0, 0, 0);
        }
      }
      for (int ni = 0; ni < 4; ++ni) {
        int col = kt * 64 + ni * 16 + lc;
        for (int r = 0; r < 4; ++r) {
          bool ok = (col <= qrow[r]) && mk[col] && qvalid[r];
          float p = ok ? __expf(c[ni][r] * 0.125f + btab[qrow[r] - col] - m[r]) * rinv[r] : 0.f;
          aout[(size_t)qrow[r] * 2048 + col] = p;
          Ps[wave * 16 + lg * 4 + r][ni * 16 + lc] = f2bf(p);
        }
      }
      __syncthreads();
      for (int ks = 0; ks < 2; ++ks) {
        s16x8 pa = *(const s16x8*)&Ps[wave * 16 + lc][ks * 32 + lg * 8];
        for (int ni = 0; ni < 4; ++ni) {
          s16x8 b = *(const s16x8*)&VTs[ni * 16 + lc][ks * 32 + lg * 8];
          yacc[ni] = __builtin_amdgcn_mfma_f32_16x16x32_bf16(pa, b, yacc[ni], 0, 0, 0);
        }
      }
    } else {
      for (int ni = 0; ni < 4; ++ni) {
        int col = kt * 64 + ni * 16 + lc;
        for (int r = 0; r < 4; ++r)
          aout[(size_t)qrow[r] * 2048 + col] = 0.f;
      }
    }
  }

  // y_ws[row][h*64+dd]
  for (int ni = 0; ni < 4; ++ni) {
    int col = h * 64 + ni * 16 + lc;
    for (int r = 0; r < 4; ++r) {
      size_t row = rowbase + wave * 16 + lg * 4 + r;
      y_ws[row * 1024 + col] = f2bf(yacc[ni][r]);
    }
  }
}

// ---------------------------------------------------------------------------
extern "C" void kernel_launch(void* const* d_in, const int* in_sizes, int n_in,
                              void* d_out, int out_size, void* d_ws, size_t ws_size,
                              hipStream_t stream)
{
  const float* x         = (const float*)d_in[0];
  const int*   mask      = (const int*)d_in[1];   // bool -> int32 per harness
  // d_in[2] rel_pos_indices, d_in[3] valid_mask: recomputed analytically
  const float* W_qkv     = (const float*)d_in[4];
  const float* W_out     = (const float*)d_in[5];
  const float* rel_table = (const float*)d_in[6];

  char* ws = (char*)d_ws;
  short* xb     = (short*)(ws);                  //  8,388,608 B
  short* WqkvT  = (short*)(ws + 8388608);        //  6,291,456 B
  short* WoutT  = (short*)(ws + 14680064);       //  2,097,152 B
  float* tableT = (float*)(ws + 16777216);       //    131,072 B
  short* qkv    = (short*)(ws + 16908288);       // 25,165,824 B
  short* y_ws   = (short*)(ws + 42074112);       //  8,388,608 B  (total ~48.1 MB)

  float* y_out    = (float*)d_out;
  float* attn_out = y_out + (size_t)2 * 2048 * 1024;

  cast_f32_bf16<<<2048, 256, 0, stream>>>(x, xb, 4194304);
  transpose_cast<<<dim3(3072 / 32, 1024 / 32), dim3(32, 8), 0, stream>>>(W_qkv, WqkvT, 1024, 3072);
  transpose_cast<<<dim3(1024 / 32, 1024 / 32), dim3(32, 8), 0, stream>>>(W_out, WoutT, 1024, 1024);
  transpose_table_k<<<128, 256, 0, stream>>>(rel_table, tableT);

  // qkv = x @ W_qkv   [4096,1024]x[1024,3072] -> bf16
  gemm_bt<false><<<dim3(24, 32), 256, 0, stream>>>(xb, WqkvT, (void*)qkv, 4096, 3072, 1024);

  attn_fused<<<dim3(32, 16, 2), 256, 0, stream>>>(qkv, mask, tableT, attn_out, y_ws);

  // y = y_ws @ W_out  [4096,1024]x[1024,1024] -> fp32 out (padded rows already 0)
  gemm_bt<true><<<dim3(8, 32), 256, 0, stream>>>(y_ws, WoutT, (void*)y_out, 4096, 1024, 1024);
}

// Round 2
// 320.591 us; speedup vs baseline: 1.6762x; 1.6762x over previous
//
#include <hip/hip_runtime.h>
#include <hip/hip_bf16.h>

// ---------------------------------------------------------------------------
// Problem: N=2, S=2048, C=1024, A=1024, H=16, d=64, MAXLEN=2048
// Outputs: y [2,2048,1024] fp32  then  attn [2,16,2048,2048] fp32 (concat flat)
// ---------------------------------------------------------------------------

typedef __attribute__((ext_vector_type(8))) short s16x8;   // 8 x bf16 bits (4 VGPR)
typedef __attribute__((ext_vector_type(4))) float f32x4;   // MFMA acc

#define NEGV (-1e30f)

static __device__ __forceinline__ short f2bf(float f) {
  unsigned u = __float_as_uint(f);
  unsigned r = (u + 0x7fffu + ((u >> 16) & 1u)) >> 16;
  return (short)r;
}

// ---------------- elementwise cast fp32 -> bf16 ----------------------------
__global__ void cast_f32_bf16(const float* __restrict__ in, short* __restrict__ out, int n) {
  int i = (blockIdx.x * 256 + threadIdx.x) * 8;
  if (i >= n) return;
  float4 a = *(const float4*)&in[i];
  float4 b = *(const float4*)&in[i + 4];
  s16x8 v;
  v[0] = f2bf(a.x); v[1] = f2bf(a.y); v[2] = f2bf(a.z); v[3] = f2bf(a.w);
  v[4] = f2bf(b.x); v[5] = f2bf(b.y); v[6] = f2bf(b.z); v[7] = f2bf(b.w);
  *(s16x8*)&out[i] = v;
}

// ---------------- transpose + cast: [R][Cc] fp32 -> [Cc][R] bf16 -----------
__global__ void transpose_cast(const float* __restrict__ in, short* __restrict__ out,
                               int R, int Cc) {
  __shared__ float tile[32][33];
  int c0 = blockIdx.x * 32, r0 = blockIdx.y * 32;
  int tx = threadIdx.x, ty = threadIdx.y;          // block (32,8)
  for (int i = 0; i < 32; i += 8)
    tile[ty + i][tx] = in[(size_t)(r0 + ty + i) * Cc + c0 + tx];
  __syncthreads();
  for (int i = 0; i < 32; i += 8)
    out[(size_t)(c0 + ty + i) * R + r0 + tx] = f2bf(tile[tx][ty + i]);
}

// ---------------- rel_table [2048][16] fp32 -> [16][2048] fp32 -------------
__global__ void transpose_table_k(const float* __restrict__ in, float* __restrict__ out) {
  int i = blockIdx.x * 256 + threadIdx.x;
  if (i >= 2048 * 16) return;
  int l = i >> 4, h = i & 15;
  out[h * 2048 + l] = in[i];
}

// ---------------- V pre-transpose: qkv V-part -> VT[n][vcol][s] bf16 -------
__global__ void vt_transpose(const short* __restrict__ qkv, short* __restrict__ vt) {
  __shared__ short tile[32][33];
  int nn = blockIdx.z;
  int c0 = blockIdx.y * 32;                        // v-col 0..1023 (= h*64+dd)
  int r0 = blockIdx.x * 32;                        // s
  int tx = threadIdx.x, ty = threadIdx.y;          // block (32,8)
  for (int i = 0; i < 32; i += 8)
    tile[ty + i][tx] = qkv[(size_t)(nn * 2048 + r0 + ty + i) * 3072 + 2048 + c0 + tx];
  __syncthreads();
  for (int i = 0; i < 32; i += 8)
    vt[(size_t)(nn * 1024 + c0 + ty + i) * 2048 + r0 + tx] = tile[tx][ty + i];
}

// ---------------- bf16 MFMA GEMM: C = A[M][K] * BT[Nn][K]^T ----------------
template<bool OUT_F32>
__global__ __launch_bounds__(256) void gemm_bt(
    const short* __restrict__ A, const short* __restrict__ BT,
    void* __restrict__ Cout, int M, int Nn, int K)
{
  __shared__ short As[128][72];
  __shared__ short Bs[128][72];
  int bn = blockIdx.x, bm = blockIdx.y;
  int tid = threadIdx.x, wave = tid >> 6, lane = tid & 63;
  int wr = wave >> 1, wc = wave & 1;
  int lc = lane & 15, lg = lane >> 4;
  f32x4 acc[4][4];
  for (int i = 0; i < 4; ++i)
    for (int j = 0; j < 4; ++j) acc[i][j] = (f32x4){0.f, 0.f, 0.f, 0.f};
  const short* Abase = A  + (size_t)(bm * 128) * K;
  const short* Bbase = BT + (size_t)(bn * 128) * K;
  for (int k0 = 0; k0 < K; k0 += 64) {
    __syncthreads();
    for (int it = 0; it < 4; ++it) {
      int lid = tid + it * 256;
      int r = lid >> 3, ck = (lid & 7) * 8;
      *(s16x8*)&As[r][ck] = *(const s16x8*)&Abase[(size_t)r * K + k0 + ck];
      *(s16x8*)&Bs[r][ck] = *(const s16x8*)&Bbase[(size_t)r * K + k0 + ck];
    }
    __syncthreads();
    for (int ks = 0; ks < 2; ++ks) {
      s16x8 af[4], bfr[4];
      for (int mi = 0; mi < 4; ++mi)
        af[mi] = *(const s16x8*)&As[wr * 64 + mi * 16 + lc][ks * 32 + lg * 8];
      for (int ni = 0; ni < 4; ++ni)
        bfr[ni] = *(const s16x8*)&Bs[wc * 64 + ni * 16 + lc][ks * 32 + lg * 8];
      for (int mi = 0; mi < 4; ++mi)
        for (int ni = 0; ni < 4; ++ni)
          acc[mi][ni] = __builtin_amdgcn_mfma_f32_16x16x32_bf16(af[mi], bfr[ni], acc[mi][ni], 0, 0, 0);
    }
  }
  int row0 = bm * 128 + wr * 64, col0 = bn * 128 + wc * 64;
  for (int mi = 0; mi < 4; ++mi)
    for (int ni = 0; ni < 4; ++ni)
      for (int r = 0; r < 4; ++r) {
        int row = row0 + mi * 16 + lg * 4 + r;
        int col = col0 + ni * 16 + lc;
        if constexpr (OUT_F32)
          ((float*)Cout)[(size_t)row * Nn + col] = acc[mi][ni][r];
        else
          ((short*)Cout)[(size_t)row * Nn + col] = f2bf(acc[mi][ni][r]);
      }
}

// ---------------- fused attention ------------------------------------------
// Flat grid 512; bid -> (qp 0..15, nh 0..31) with bid%8 = nh%8 (XCD affinity:
// blocks sharing (n,h) K/V land on one XCD's L2). Each block handles the
// BALANCED pair of q-tiles {qp, 31-qp}: 33 causal k-tiles per pass, constant.
// Swapped QK^T (mfma(K,Q)): lane owns ONE q-row (lc) with 4 consecutive
// k-cols per acc reg -> float4 attn stores, scalar m/l, 2-shuffle reduce.
__global__ __launch_bounds__(256) void attn_fused(
    const short* __restrict__ qkv,     // [4096][3072] bf16
    const short* __restrict__ vt,      // [2][1024][2048] bf16 (V^T)
    const int*   __restrict__ mask,    // [2][2048]
    const float* __restrict__ tableT,  // [16][2048]
    float* __restrict__ attn_out,      // [2][16][2048][2048]
    short* __restrict__ y_ws)          // [4096][1024] bf16
{
  int bid = blockIdx.x;
  int nh_lo = bid & 7, qp = (bid >> 3) & 15, nh_hi = bid >> 7;
  int nh = nh_hi * 8 + nh_lo;
  int n = nh >> 4, h = nh & 15;
  int tid = threadIdx.x, wave = tid >> 6, lane = tid & 63;
  int lc = lane & 15, lg = lane >> 4;

  __shared__ short Qs[64][72];
  __shared__ short Ks[64][72];
  __shared__ short VTs[64][72];   // [dd][k], staged from pre-transposed VT
  __shared__ short Ps[64][72];
  __shared__ float btab[2048];
  __shared__ unsigned char mk[2048];

  for (int i = tid; i < 2048; i += 256) {
    btab[i] = tableT[h * 2048 + i];
    mk[i] = (unsigned char)(mask[n * 2048 + i] != 0);
  }

  float* aout = attn_out + (size_t)(n * 16 + h) * 2048 * 2048;
  const short* vtbase = vt + (size_t)(n * 1024 + h * 64) * 2048;

  for (int half = 0; half < 2; ++half) {
    int qt = half ? (31 - qp) : qp;
    size_t rowbase = (size_t)(n * 2048 + qt * 64);

    __syncthreads();                     // covers btab/mk on first pass, Qs reuse after
    const short* qbase = qkv + rowbase * 3072 + h * 64;
    for (int it = 0; it < 2; ++it) {
      int lid = tid + it * 256;
      int r = lid >> 3, ck = (lid & 7) * 8;
      *(s16x8*)&Qs[r][ck] = *(const s16x8*)&qbase[(size_t)r * 3072 + ck];
    }
    __syncthreads();

    s16x8 aq[2];                         // lane: Q[q=wave*16+lc][d=ks*32+lg*8..+7]
    for (int ks = 0; ks < 2; ++ks)
      aq[ks] = *(const s16x8*)&Qs[wave * 16 + lc][ks * 32 + lg * 8];

    int qrow = qt * 64 + wave * 16 + lc; // this lane's q-row
    float m = NEGV, l = 0.f;

    // ---------------- pass 1: row max + sum ----------------
    for (int kt = 0; kt <= qt; ++kt) {
      __syncthreads();
      const short* kbase = qkv + (size_t)(n * 2048 + kt * 64) * 3072 + 1024 + h * 64;
      for (int it = 0; it < 2; ++it) {
        int lid = tid + it * 256;
        int r = lid >> 3, ck = (lid & 7) * 8;
        *(s16x8*)&Ks[r][ck] = *(const s16x8*)&kbase[(size_t)r * 3072 + ck];
      }
      __syncthreads();

      f32x4 c[4];
      for (int ni = 0; ni < 4; ++ni) {
        c[ni] = (f32x4){0.f, 0.f, 0.f, 0.f};
        for (int ks = 0; ks < 2; ++ks) {
          s16x8 kf = *(const s16x8*)&Ks[ni * 16 + lc][ks * 32 + lg * 8];
          c[ni] = __builtin_amdgcn_mfma_f32_16x16x32_bf16(kf, aq[ks], c[ni], 0, 0, 0);
        }
      }
      // c[ni][r] = S[k = kt*64+ni*16+lg*4+r][q = qrow]
      float vals[4][4], tmax = NEGV;
      for (int ni = 0; ni < 4; ++ni)
        for (int r = 0; r < 4; ++r) {
          int col = kt * 64 + ni * 16 + lg * 4 + r;
          bool ok = (col <= qrow) && mk[col];
          float v = ok ? c[ni][r] * 0.125f + btab[qrow - col] : NEGV;
          vals[ni][r] = v;
          tmax = fmaxf(tmax, v);
        }
      tmax = fmaxf(tmax, __shfl_xor(tmax, 16));
      tmax = fmaxf(tmax, __shfl_xor(tmax, 32));
      float mn = fmaxf(m, tmax);
      float s = 0.f;
      for (int ni = 0; ni < 4; ++ni)
        for (int r = 0; r < 4; ++r) s += __expf(vals[ni][r] - mn);
      s += __shfl_xor(s, 16);
      s += __shfl_xor(s, 32);
      l = l * __expf(m - mn) + s;
      m = mn;
    }

    float rinv = 1.0f / l;
    bool qv = (mk[qrow] != 0);

    f32x4 yacc[4];
    for (int ni = 0; ni < 4; ++ni) yacc[ni] = (f32x4){0.f, 0.f, 0.f, 0.f};

    // ---------------- pass 2: normalized attn (float4) + PV ----------------
    for (int kt = 0; kt <= qt; ++kt) {
      __syncthreads();
      const short* kbase = qkv + (size_t)(n * 2048 + kt * 64) * 3072 + 1024 + h * 64;
      for (int it = 0; it < 2; ++it) {
        int lid = tid + it * 256;
        int r = lid >> 3, ck = (lid & 7) * 8;
        *(s16x8*)&Ks[r][ck]  = *(const s16x8*)&kbase[(size_t)r * 3072 + ck];
        *(s16x8*)&VTs[r][ck] = *(const s16x8*)&vtbase[(size_t)r * 2048 + kt * 64 + ck];
      }
      __syncthreads();

      f32x4 c[4];
      for (int ni = 0; ni < 4; ++ni) {
        c[ni] = (f32x4){0.f, 0.f, 0.f, 0.f};
        for (int ks = 0; ks < 2; ++ks) {
          s16x8 kf = *(const s16x8*)&Ks[ni * 16 + lc][ks * 32 + lg * 8];
          c[ni] = __builtin_amdgcn_mfma_f32_16x16x32_bf16(kf, aq[ks], c[ni], 0, 0, 0);
        }
      }
      for (int ni = 0; ni < 4; ++ni) {
        float4 p4;
        float pv[4];
        for (int r = 0; r < 4; ++r) {
          int col = kt * 64 + ni * 16 + lg * 4 + r;
          bool ok = (col <= qrow) && mk[col] && qv;
          float p = ok ? __expf(c[ni][r] * 0.125f + btab[qrow - col] - m) * rinv : 0.f;
          pv[r] = p;
          Ps[wave * 16 + lc][ni * 16 + lg * 4 + r] = f2bf(p);
        }
        p4.x = pv[0]; p4.y = pv[1]; p4.z = pv[2]; p4.w = pv[3];
        *(float4*)&aout[(size_t)qrow * 2048 + kt * 64 + ni * 16 + lg * 4] = p4;
      }
      __syncthreads();
      for (int ks = 0; ks < 2; ++ks) {
        s16x8 pa = *(const s16x8*)&Ps[wave * 16 + lc][ks * 32 + lg * 8];
        for (int ni = 0; ni < 4; ++ni) {
          s16x8 vfr = *(const s16x8*)&VTs[ni * 16 + lc][ks * 32 + lg * 8];
          yacc[ni] = __builtin_amdgcn_mfma_f32_16x16x32_bf16(pa, vfr, yacc[ni], 0, 0, 0);
        }
      }
    }

    // ---------------- zero upper triangle (float4, all threads) ------------
    int zc0 = (qt + 1) * 64;
    if (zc0 < 2048) {
      float4 z4 = {0.f, 0.f, 0.f, 0.f};
      for (int rr = 0; rr < 64; ++rr) {
        float* dst = aout + (size_t)(qt * 64 + rr) * 2048;
        for (int cc = zc0 + (tid << 2); cc < 2048; cc += 1024)
          *(float4*)&dst[cc] = z4;
      }
    }

    // ---------------- y store ----------------------------------------------
    for (int ni = 0; ni < 4; ++ni) {
      int col = h * 64 + ni * 16 + lc;
      for (int r = 0; r < 4; ++r) {
        size_t row = rowbase + wave * 16 + lg * 4 + r;
        y_ws[row * 1024 + col] = f2bf(yacc[ni][r]);
      }
    }
  }
}

// ---------------------------------------------------------------------------
extern "C" void kernel_launch(void* const* d_in, const int* in_sizes, int n_in,
                              void* d_out, int out_size, void* d_ws, size_t ws_size,
                              hipStream_t stream)
{
  const float* x         = (const float*)d_in[0];
  const int*   mask      = (const int*)d_in[1];
  const float* W_qkv     = (const float*)d_in[4];
  const float* W_out     = (const float*)d_in[5];
  const float* rel_table = (const float*)d_in[6];

  char* ws = (char*)d_ws;
  short* xb     = (short*)(ws);                  //  8,388,608 B (reused as VT after gemm1)
  short* WqkvT  = (short*)(ws + 8388608);        //  6,291,456 B
  short* WoutT  = (short*)(ws + 14680064);       //  2,097,152 B
  float* tableT = (float*)(ws + 16777216);       //    131,072 B
  short* qkv    = (short*)(ws + 16908288);       // 25,165,824 B
  short* y_ws   = (short*)(ws + 42074112);       //  8,388,608 B
  short* vt     = xb;                            // exact size match: 2*1024*2048*2 B

  float* y_out    = (float*)d_out;
  float* attn_out = y_out + (size_t)2 * 2048 * 1024;

  cast_f32_bf16<<<2048, 256, 0, stream>>>(x, xb, 4194304);
  transpose_cast<<<dim3(3072 / 32, 1024 / 32), dim3(32, 8), 0, stream>>>(W_qkv, WqkvT, 1024, 3072);
  transpose_cast<<<dim3(1024 / 32, 1024 / 32), dim3(32, 8), 0, stream>>>(W_out, WoutT, 1024, 1024);
  transpose_table_k<<<128, 256, 0, stream>>>(rel_table, tableT);

  gemm_bt<false><<<dim3(24, 32), 256, 0, stream>>>(xb, WqkvT, (void*)qkv, 4096, 3072, 1024);

  vt_transpose<<<dim3(64, 32, 2), dim3(32, 8), 0, stream>>>(qkv, vt);

  attn_fused<<<512, 256, 0, stream>>>(qkv, vt, mask, tableT, attn_out, y_ws);

  gemm_bt<true><<<dim3(8, 32), 256, 0, stream>>>(y_ws, WoutT, (void*)y_out, 4096, 1024, 1024);
}